// Round 9
// baseline (361.602 us; speedup 1.0000x reference)
//
#include <hip/hip_runtime.h>

#define N_SEQ 2048
#define M_FFT 4096
#define D1    1536
#define NH    8
#define HD    192
#define ED    512

typedef __bf16 bf16;
typedef __bf16 bf16x4 __attribute__((ext_vector_type(4)));
typedef __bf16 bf16x8 __attribute__((ext_vector_type(8)));
typedef float  floatx4 __attribute__((ext_vector_type(4)));

enum { MODE_PLAIN = 0, MODE_SILU_UV = 1, MODE_AT = 3, MODE_RPE = 4 };

__device__ __forceinline__ void gload16(const void* g, void* l) {
    __builtin_amdgcn_global_load_lds(
        (const __attribute__((address_space(1))) void*)g,
        (__attribute__((address_space(3))) void*)l, 16, 0, 0);
}

// ---------------------------------------------------------------------------
// bf16 MFMA GEMM (m97 structure): C = epilogue(A(MxK) @ Bw(NcxK)^T + bias)
// MODE_RPE: val = acc*scale_prev[row] + bias; atomic row sum-sq; relu; bf16.
// MODE_AT : val = acc*scale_prev[row] + bias; fp32 transposed store.
// ---------------------------------------------------------------------------
template<int MODE, typename OutT>
__global__ __launch_bounds__(256) void gemm_bf16(
    const bf16* __restrict__ A, const bf16* __restrict__ Bw,
    const float* __restrict__ bias, const float* __restrict__ bias2,
    OutT* __restrict__ C, OutT* __restrict__ C2,
    int M, int Nc, int K,
    const float* __restrict__ scale_in, float* __restrict__ sumsq_out)
{
    __shared__ __align__(16) bf16 As[128 * 32];
    __shared__ __align__(16) bf16 Bs[128 * 32];

    const int tid  = threadIdx.x;
    const int row0 = blockIdx.y * 128;
    const int col0 = blockIdx.x * 128;
    const int wid  = tid >> 6;
    const int lane = tid & 63;
    const int lm   = lane & 15;
    const int lk   = lane >> 4;
    const int wm   = wid >> 1;
    const int wn   = wid & 1;
    const int ldrow  = tid >> 2;
    const int ldcol8 = (tid & 3) * 8;

    floatx4 acc[4][4] = {};

    const bf16* Ag = A  + ((size_t)(row0 + ldrow)) * K + ldcol8;
    const bf16* Bg = Bw + ((size_t)(col0 + ldrow)) * K + ldcol8;
    bf16* AsW = As + (wid * 16) * 32;
    bf16* BsW = Bs + (wid * 16) * 32;

    for (int k0 = 0; k0 < K; k0 += 32) {
        gload16(Ag + k0, AsW);
        gload16(Ag + (size_t)64 * K + k0, AsW + 64 * 32);
        gload16(Bg + k0, BsW);
        gload16(Bg + (size_t)64 * K + k0, BsW + 64 * 32);
        __syncthreads();

        bf16x8 af[4], bfr[4];
        #pragma unroll
        for (int mi = 0; mi < 4; ++mi)
            af[mi] = *(const bf16x8*)&As[(wm * 64 + mi * 16 + lm) * 32 + lk * 8];
        #pragma unroll
        for (int nj = 0; nj < 4; ++nj)
            bfr[nj] = *(const bf16x8*)&Bs[(wn * 64 + nj * 16 + lm) * 32 + lk * 8];
        #pragma unroll
        for (int mi = 0; mi < 4; ++mi)
            #pragma unroll
            for (int nj = 0; nj < 4; ++nj)
                acc[mi][nj] = __builtin_amdgcn_mfma_f32_16x16x32_bf16(
                    af[mi], bfr[nj], acc[mi][nj], 0, 0, 0);
        __syncthreads();
    }

    const float* bs = bias;
    OutT* dst = C;
    int cadj = 0;
    if (MODE == MODE_SILU_UV && col0 >= D1) { bs = bias2; dst = C2; cadj = D1; }

    float bcol[4];
    #pragma unroll
    for (int nj = 0; nj < 4; ++nj)
        bcol[nj] = bs[col0 - cadj + wn * 64 + nj * 16 + lm];

    if (MODE == MODE_RPE) {
        #pragma unroll
        for (int mi = 0; mi < 4; ++mi) {
            #pragma unroll
            for (int r = 0; r < 4; ++r) {
                const int row = row0 + wm * 64 + mi * 16 + lk * 4 + r;
                float sc = 1.0f;
                if (scale_in)
                    sc = 1.0f / (sqrtf(scale_in[row]) * 0.04419417382415922f + 1e-8f);
                float ssq = 0.0f;
                #pragma unroll
                for (int nj = 0; nj < 4; ++nj) {
                    const int col = col0 + wn * 64 + nj * 16 + lm;
                    float val = acc[mi][nj][r] * sc + bcol[nj];
                    ssq += val * val;
                    ((bf16*)C)[(size_t)row * Nc + col] = (bf16)fmaxf(val, 0.0f);
                }
                ssq += __shfl_xor(ssq, 1, 64);
                ssq += __shfl_xor(ssq, 2, 64);
                ssq += __shfl_xor(ssq, 4, 64);
                ssq += __shfl_xor(ssq, 8, 64);
                if (lm == 0) atomicAdd(&sumsq_out[row], ssq);
            }
        }
        return;
    }

    #pragma unroll
    for (int mi = 0; mi < 4; ++mi) {
        const int rbase = row0 + wm * 64 + mi * 16 + lk * 4;
        float sc[4];
        #pragma unroll
        for (int r = 0; r < 4; ++r) {
            sc[r] = 1.0f;
            if (MODE == MODE_AT && scale_in)
                sc[r] = 1.0f / (sqrtf(scale_in[rbase + r]) * 0.04419417382415922f + 1e-8f);
        }
        #pragma unroll
        for (int nj = 0; nj < 4; ++nj) {
            const int col = col0 - cadj + wn * 64 + nj * 16 + lm;
            float vals[4];
            #pragma unroll
            for (int r = 0; r < 4; ++r) {
                float val = acc[mi][nj][r] * sc[r] + bcol[nj];
                if (MODE == MODE_SILU_UV)
                    val = val / (1.0f + __expf(-val));
                vals[r] = val;
            }
            if (MODE == MODE_SILU_UV) {
                int b = rbase >> 11, s = rbase & 2047;
                bf16x4 o;
                #pragma unroll
                for (int r = 0; r < 4; ++r) o[r] = (bf16)vals[r];
                *(bf16x4*)&((bf16*)dst)[((size_t)(b * D1 + col)) * N_SEQ + s] = o;
            } else if (MODE == MODE_AT) {
                float4 o = make_float4(vals[0], vals[1], vals[2], vals[3]);
                *(float4*)&((float*)C)[(size_t)col * M + rbase] = o;
            } else {
                #pragma unroll
                for (int r = 0; r < 4; ++r)
                    C[(size_t)(rbase + r) * Nc + col] = (OutT)vals[r];
            }
        }
    }
}

// ---------------------------------------------------------------------------
// mega-prologue: x convert (4096 blk) + 5 weight converts (3840 blk) +
// sumsq zero (12 blk) + RPE input layer w/ srms (4096 blk)
// ---------------------------------------------------------------------------
__global__ __launch_bounds__(256) void f2b_all_kernel(
    const float* __restrict__ x,  const float* __restrict__ s0,
    const float* __restrict__ s1, const float* __restrict__ s2,
    const float* __restrict__ s3, const float* __restrict__ s4,
    const float* __restrict__ Wp, const float* __restrict__ bp,
    bf16* __restrict__ x_bf, bf16* __restrict__ w_bf,
    float* __restrict__ sumsq, bf16* __restrict__ g0)
{
    const int bid = blockIdx.x;
    const int tid = threadIdx.x;
    __shared__ float red[4];

    if (bid < 7936) {
        const float* src;
        bf16* dst;
        size_t off;
        if (bid < 4096) {
            src = x; dst = x_bf; off = (size_t)bid * 1024;
        } else {
            int t = bid - 4096;
            int seg = t / 768;
            src = seg == 0 ? s0 : seg == 1 ? s1 : seg == 2 ? s2
                : seg == 3 ? s3 : s4;
            dst = w_bf + (size_t)seg * 786432;
            off = (size_t)(t % 768) * 1024;
        }
        size_t i = off + (size_t)tid * 4;
        float4 f = *(const float4*)(src + i);
        union { bf16 h[4]; short4 s; } u4;
        u4.h[0] = (bf16)f.x; u4.h[1] = (bf16)f.y;
        u4.h[2] = (bf16)f.z; u4.h[3] = (bf16)f.w;
        *(short4*)(dst + i) = u4.s;
    } else if (bid < 7948) {
        size_t i = (size_t)(bid - 7936) * 1024 + (size_t)tid * 4;
        *(float4*)(sumsq + i) = make_float4(0.f, 0.f, 0.f, 0.f);
    } else {
        const int j = bid - 7948;
        float idxv = (j < N_SEQ) ? (float)j
                                 : (j == N_SEQ ? 0.0f : (float)(j - 2 * N_SEQ));
        float h1 = idxv * Wp[tid] + bp[tid];
        float h2 = idxv * Wp[tid + 256] + bp[tid + 256];
        float ss = h1 * h1 + h2 * h2;
        #pragma unroll
        for (int off = 32; off > 0; off >>= 1) ss += __shfl_down(ss, off, 64);
        if ((tid & 63) == 0) red[tid >> 6] = ss;
        __syncthreads();
        float tot = red[0] + red[1] + red[2] + red[3];
        float scale = 1.0f / (sqrtf(tot) * 0.04419417382415922f + 1e-8f);
        g0[(size_t)j * ED + tid]       = (bf16)fmaxf(h1 * scale, 0.0f);
        g0[(size_t)j * ED + tid + 256] = (bf16)fmaxf(h2 * scale, 0.0f);
    }
}

// ---------------------------------------------------------------------------
// Radix-16 FFT, radix-4-factored butterflies, register tree twiddles.
// Scalar float2 complex math (R7 form — packed ext-vector regressed, R8).
// ---------------------------------------------------------------------------
#define FFT_LDS_SZ 4381
#define CC1 0.9238795325112867f
#define SS1 0.3826834323650898f
#define RR2 0.7071067811865476f

__device__ __forceinline__ int fpad(int i) { return i + (i >> 4) + 2 * (i >> 8); }

__device__ __forceinline__ float2 cmul(float2 a, float2 b) {
    return make_float2(a.x * b.x - a.y * b.y, a.x * b.y + a.y * b.x);
}
__device__ __forceinline__ float2 cadd(float2 a, float2 b) {
    return make_float2(a.x + b.x, a.y + b.y);
}
__device__ __forceinline__ float2 csub(float2 a, float2 b) {
    return make_float2(a.x - b.x, a.y - b.y);
}
__device__ __forceinline__ float2 cneg_i(float2 a) { return make_float2(a.y, -a.x); }
__device__ __forceinline__ float2 cpos_i(float2 a) { return make_float2(-a.y, a.x); }
__host__ __device__ constexpr int brev4(int t) {
    return ((t & 1) << 3) | ((t & 2) << 1) | ((t & 4) >> 1) | ((t & 8) >> 3);
}

template<bool HZ>
__device__ __forceinline__ void fft16_dif_r4(float2 x[16]) {
    const float2 W1 = make_float2( CC1, -SS1);
    const float2 W2 = make_float2( RR2, -RR2);
    const float2 W3 = make_float2( SS1, -CC1);
    const float2 W6 = make_float2(-RR2, -RR2);
    const float2 W9 = make_float2(-CC1,  SS1);
    #pragma unroll
    for (int n = 0; n < 4; ++n) {
        float2 A, B, C, D;
        if (HZ) { A = x[n]; C = x[n]; B = x[n + 4]; D = x[n + 4]; }
        else {
            A = cadd(x[n], x[n + 8]);  C = csub(x[n], x[n + 8]);
            B = cadd(x[n + 4], x[n + 12]); D = csub(x[n + 4], x[n + 12]);
        }
        float2 s = csub(A, B);
        float2 nid = cneg_i(D);
        float2 m = cadd(C, nid);
        float2 p = csub(C, nid);
        x[n] = cadd(A, B);
        if (n == 0)      { x[4] = s;            x[8]  = m;           x[12] = p; }
        else if (n == 1) { x[5] = cmul(s, W2);  x[9]  = cmul(m, W1); x[13] = cmul(p, W3); }
        else if (n == 2) { x[6] = cneg_i(s);    x[10] = cmul(m, W2); x[14] = cmul(p, W6); }
        else             { x[7] = cmul(s, W6);  x[11] = cmul(m, W3); x[15] = cmul(p, W9); }
    }
    #pragma unroll
    for (int q = 0; q < 16; q += 4) {
        float2 a = x[q], b = x[q + 1], c = x[q + 2], d = x[q + 3];
        float2 a1 = cadd(a, c), c1 = csub(a, c);
        float2 b1 = cadd(b, d), d1 = cneg_i(csub(b, d));
        x[q]     = cadd(a1, b1);
        x[q + 1] = csub(a1, b1);
        x[q + 2] = cadd(c1, d1);
        x[q + 3] = csub(c1, d1);
    }
}

template<bool HALF_OUT>
__device__ __forceinline__ void fft16_dit_inv_r4(float2 x[16]) {
    const float2 V1 = make_float2( CC1, SS1);
    const float2 V2 = make_float2( RR2, RR2);
    const float2 V3 = make_float2( SS1, CC1);
    const float2 V6 = make_float2(-RR2, RR2);
    #pragma unroll
    for (int q = 0; q < 16; q += 4) {
        float2 a = x[q], b = x[q + 1], c = x[q + 2], d = x[q + 3];
        float2 a1 = cadd(a, b), b1 = csub(a, b);
        float2 c1 = cadd(c, d), d1 = csub(c, d);
        float2 t = cpos_i(d1);
        x[q]     = cadd(a1, c1);
        x[q + 2] = csub(a1, c1);
        x[q + 1] = cadd(b1, t);
        x[q + 3] = csub(b1, t);
    }
    #pragma unroll
    for (int n = 0; n < 4; ++n) {
        float2 t1, t2;
        if (n == 0)      { t1 = x[4];             t2 = x[12]; }
        else if (n == 1) { t1 = cmul(x[5],  V2);  t2 = cmul(x[13], V2); }
        else if (n == 2) { t1 = cpos_i(x[6]);     t2 = cpos_i(x[14]); }
        else             { t1 = cmul(x[7],  V6);  t2 = cmul(x[15], V6); }
        float2 P = cadd(x[n], t1), Q = csub(x[n], t1);
        float2 R = cadd(x[n + 8], t2), S = csub(x[n + 8], t2);
        float2 t, u;
        if (n == 0)      { t = R;            u = S; }
        else if (n == 1) { t = cmul(R, V1);  u = cmul(S, V1); }
        else if (n == 2) { t = cmul(R, V2);  u = cmul(S, V2); }
        else             { t = cmul(R, V3);  u = cmul(S, V3); }
        float2 iu = cpos_i(u);
        x[n]     = cadd(P, t);
        x[n + 4] = cadd(Q, iu);
        if (!HALF_OUT) {
            x[n + 8]  = csub(P, t);
            x[n + 12] = csub(Q, iu);
        }
    }
}

__device__ __forceinline__ void stage_twiddle_tree(
    float2 v[16], int j, float rden, float sgn)
{
    float s, c;
    __sincosf(sgn * 6.283185307179586f * (float)j * rden, &s, &c);
    float2 w[16];
    w[1] = make_float2(c, s);
    w[2] = cmul(w[1], w[1]);
    w[3] = cmul(w[1], w[2]);
    w[4] = cmul(w[2], w[2]);
    w[5] = cmul(w[1], w[4]);
    w[6] = cmul(w[2], w[4]);
    w[7] = cmul(w[3], w[4]);
    w[8] = cmul(w[4], w[4]);
    #pragma unroll
    for (int t = 9; t < 16; ++t) w[t] = cmul(w[t - 8], w[8]);
    #pragma unroll
    for (int tau = 1; tau < 16; ++tau)
        v[brev4(tau)] = cmul(v[brev4(tau)], w[tau]);
}

template<bool HALF_ZERO>
__device__ void fft4096_fwd(float2* d, int tid)
{
    float2 v[16];
    {
        const int j = tid;
        if (HALF_ZERO) {
            #pragma unroll
            for (int t = 0; t < 8; ++t) v[t] = d[fpad(j + (t << 8))];
            fft16_dif_r4<true>(v);
        } else {
            #pragma unroll
            for (int t = 0; t < 16; ++t) v[t] = d[fpad(j + (t << 8))];
            fft16_dif_r4<false>(v);
        }
        stage_twiddle_tree(v, j, 1.0f / 4096.0f, -1.0f);
        #pragma unroll
        for (int p = 0; p < 16; ++p) d[fpad(j + (p << 8))] = v[p];
    }
    __syncthreads();
    {
        const int base = ((tid >> 4) << 8) + (tid & 15);
        #pragma unroll
        for (int t = 0; t < 16; ++t) v[t] = d[fpad(base + (t << 4))];
        fft16_dif_r4<false>(v);
        stage_twiddle_tree(v, tid & 15, 1.0f / 256.0f, -1.0f);
        #pragma unroll
        for (int p = 0; p < 16; ++p) d[fpad(base + (p << 4))] = v[p];
    }
    __syncthreads();
    {
        const int base = tid << 4;
        #pragma unroll
        for (int t = 0; t < 16; ++t) v[t] = d[fpad(base + t)];
        fft16_dif_r4<false>(v);
        #pragma unroll
        for (int p = 0; p < 16; ++p) d[fpad(base + p)] = v[p];
    }
    __syncthreads();
}

// ---------------------------------------------------------------------------
__global__ __launch_bounds__(256) void fft_a_kernel(
    const float* __restrict__ a_t, float2* __restrict__ Wspec)
{
    __shared__ float2 data[FFT_LDS_SZ];
    const int tid = threadIdx.x;
    const int h = blockIdx.x / 96, dp = blockIdx.x % 96;

    const float* r0 = a_t + ((size_t)(h * HD + 2 * dp)) * M_FFT;
    const float* r1 = r0 + M_FFT;

    for (int j = tid; j < 4096; j += 256) data[fpad(j)] = make_float2(r0[j], r1[j]);
    __syncthreads();
    fft4096_fwd<false>(data, tid);

    float2* outrow = Wspec + (size_t)blockIdx.x * 4096;
    for (int j = tid; j < 4096; j += 256) outrow[j] = data[fpad(j)];
}

// ---------------------------------------------------------------------------
__global__ __launch_bounds__(256) void fft_conv_kernel(
    const bf16* __restrict__ v_t, const float2* __restrict__ Wspec,
    const bf16* __restrict__ u_t, bf16* __restrict__ gated_t)
{
    __shared__ float2 data[FFT_LDS_SZ];
    const int tid = threadIdx.x;
    const int bx = blockIdx.x;
    const int b  = bx / 768;
    const int r  = bx % 768;
    const int h  = r / 96, dp = r % 96;
    const int ch = h * HD + 2 * dp;

    const bf16* z0 = v_t + ((size_t)(b * D1 + ch)) * N_SEQ;
    const bf16* z1 = z0 + N_SEQ;

    {
        const int s = tid * 8;
        bf16x8 a0 = *(const bf16x8*)(z0 + s);
        bf16x8 a1 = *(const bf16x8*)(z1 + s);
        #pragma unroll
        for (int i = 0; i < 8; ++i)
            data[fpad(s + i)] = make_float2((float)a0[i], (float)a1[i]);
    }
    __syncthreads();

    fft4096_fwd<true>(data, tid);

    // fused per-bin pointwise + inverse stage 1
    const float2* Wrow = Wspec + (size_t)r * 4096;
    float2 v[16];
    {
        const int base = tid << 4;
        #pragma unroll
        for (int i = 0; i < 16; ++i) {
            const int p  = base + i;
            const int k  = __brev((unsigned)p) >> 20;
            const int km = (4096 - k) & 4095;
            const int p2 = __brev((unsigned)km) >> 20;
            float2 Zk = data[fpad(p)];
            float2 Zm = data[fpad(p2)];
            float2 Wk = Wrow[p];
            float2 Wm = Wrow[p2];
            float2 V0 = make_float2(0.5f * (Zk.x + Zm.x), 0.5f * (Zk.y - Zm.y));
            float2 V1 = make_float2(0.5f * (Zk.y + Zm.y), 0.5f * (Zm.x - Zk.x));
            float2 A0 = make_float2(0.5f * (Wk.x + Wm.x), 0.5f * (Wk.y - Wm.y));
            float2 A1 = make_float2(0.5f * (Wk.y + Wm.y), 0.5f * (Wm.x - Wk.x));
            float2 P = cmul(V0, A0), Q = cmul(V1, A1);
            v[i] = make_float2(P.x - Q.y, P.y + Q.x);   // Y = P + iQ
        }
        __syncthreads();
        fft16_dit_inv_r4<false>(v);
        #pragma unroll
        for (int i = 0; i < 16; ++i) data[fpad(base + i)] = v[i];
    }
    __syncthreads();
    {   // inverse stage 2
        const int base = ((tid >> 4) << 8) + (tid & 15);
        #pragma unroll
        for (int p = 0; p < 16; ++p) v[p] = data[fpad(base + (p << 4))];
        stage_twiddle_tree(v, tid & 15, 1.0f / 256.0f, 1.0f);
        fft16_dit_inv_r4<false>(v);
        #pragma unroll
        for (int t = 0; t < 16; ++t) data[fpad(base + (t << 4))] = v[t];
    }
    __syncthreads();
    {   // inverse stage 3, lower half only
        const int j = tid;
        #pragma unroll
        for (int p = 0; p < 16; ++p) v[p] = data[fpad(j + (p << 8))];
        stage_twiddle_tree(v, j, 1.0f / 4096.0f, 1.0f);
        fft16_dit_inv_r4<true>(v);
        #pragma unroll
        for (int t = 0; t < 8; ++t) data[fpad(j + (t << 8))] = v[t];
    }
    __syncthreads();

    const float inv_m = 1.0f / 4096.0f;
    const bf16* u0 = u_t + ((size_t)(b * D1 + ch)) * N_SEQ;
    const bf16* u1 = u0 + N_SEQ;
    bf16* g0 = gated_t + ((size_t)(b * D1 + ch)) * N_SEQ;
    bf16* g1 = g0 + N_SEQ;
    {
        const int t = tid * 8;
        bf16x8 ua = *(const bf16x8*)(u0 + t);
        bf16x8 ub = *(const bf16x8*)(u1 + t);
        bf16x8 oa, ob;
        #pragma unroll
        for (int i = 0; i < 8; ++i) {
            float2 y = data[fpad(t + i)];
            oa[i] = (bf16)(y.x * inv_m * (float)ua[i]);
            ob[i] = (bf16)(y.y * inv_m * (float)ub[i]);
        }
        *(bf16x8*)(g0 + t) = oa;
        *(bf16x8*)(g1 + t) = ob;
    }
}

// ---------------------------------------------------------------------------
__global__ __launch_bounds__(256) void transpose_cs_kernel(
    const bf16* __restrict__ in, bf16* __restrict__ outp)
{
    __shared__ bf16 tile[64 * 68];
    const int c0 = blockIdx.x * 64;
    const int m0 = blockIdx.y * 64;
    const int b  = m0 >> 11;
    const int s0 = m0 & 2047;
    const int tid = threadIdx.x;
    const int cl = tid >> 4;
    const int sc = (tid & 15) * 4;
    #pragma unroll
    for (int p = 0; p < 4; ++p) {
        int c = p * 16 + cl;
        bf16x4 v = *(const bf16x4*)&in[((size_t)(b * D1 + c0 + c)) * N_SEQ + s0 + sc];
        *(bf16x4*)&tile[c * 68 + sc] = v;
    }
    __syncthreads();
    const int sl = tid >> 4;
    const int cc = (tid & 15) * 4;
    #pragma unroll
    for (int p = 0; p < 4; ++p) {
        int s = p * 16 + sl;
        bf16x4 o;
        #pragma unroll
        for (int j = 0; j < 4; ++j) o[j] = tile[(cc + j) * 68 + s];
        *(bf16x4*)&outp[((size_t)(m0 + s)) * D1 + c0 + cc] = o;
    }
}

// ---------------------------------------------------------------------------
extern "C" void kernel_launch(void* const* d_in, const int* in_sizes, int n_in,
                              void* d_out, int out_size, void* d_ws, size_t ws_size,
                              hipStream_t stream)
{
    const float* x  = (const float*)d_in[0];
    const float* Wu = (const float*)d_in[1];
    const float* bu = (const float*)d_in[2];
    const float* Wv = (const float*)d_in[3];
    const float* bv = (const float*)d_in[4];
    const float* Wo = (const float*)d_in[5];
    const float* bo = (const float*)d_in[6];
    const float* Wp = (const float*)d_in[7];
    const float* bp = (const float*)d_in[8];
    const float* Wl = (const float*)d_in[9];
    const float* bl = (const float*)d_in[10];
    const float* Wr = (const float*)d_in[11];
    const float* br = (const float*)d_in[12];
    float* out = (float*)d_out;

    float* ws      = (float*)d_ws;
    float* a_t     = ws;                       // 1536*4096 fp32
    float* Wspec   = a_t   + 6291456;          // 768 x 4096 float2
    float* sumsq   = Wspec + 6291456;          // 3 x 4096 fp32
    bf16*  bfws    = (bf16*)(sumsq + 12288);
    bf16*  x_bf    = bfws;                     // 8192*512
    bf16*  w_bf    = x_bf    + 4194304;        // 5 x 786432: Wu,Wv,Wo,Wl,Wr
    bf16*  Wuv_bf  = w_bf;                     // stacked [Wu;Wv] 3072 x 512
    bf16*  Wo_bf   = w_bf    + 2 * 786432;
    bf16*  Wl_bf   = Wo_bf   + 786432;
    bf16*  Wr_bf   = Wl_bf   + 786432;
    bf16*  gA      = Wr_bf   + 786432;         // 4096*512
    bf16*  gB      = gA      + 2097152;        // 4096*512
    bf16*  u_t     = gB      + 2097152;        // 8192*1536 [b][c][s]
    bf16*  v_t     = u_t     + 12582912;       // 8192*1536 [b][c][s]
    bf16*  gated_t = v_t     + 12582912;       // 8192*1536 [b][c][s]
    bf16*  gated   = gated_t + 12582912;       // 8192*1536 [m][c]

    dim3 blk(256);

    f2b_all_kernel<<<4096 + 5 * 768 + 12 + 4096, blk, 0, stream>>>(
        x, Wu, Wv, Wo, Wl, Wr, Wp, bp, x_bf, w_bf, sumsq, gA);

    gemm_bf16<MODE_SILU_UV, bf16><<<dim3(24, 64), blk, 0, stream>>>(
        x_bf, Wuv_bf, bu, bv, u_t, v_t, 8192, 2 * D1, ED, nullptr, nullptr);

    bf16* gin = gA;
    bf16* gout = gB;
    for (int i = 0; i < 3; ++i) {
        const float* sin_p = (i == 0) ? nullptr : sumsq + (size_t)(i - 1) * 4096;
        gemm_bf16<MODE_RPE, bf16><<<dim3(4, 32), blk, 0, stream>>>(
            gin, Wl_bf + (size_t)i * ED * ED, bl + (size_t)i * ED, nullptr,
            gout, nullptr, 4096, ED, ED, sin_p, sumsq + (size_t)i * 4096);
        bf16* t = gin; gin = gout; gout = t;
    }
    gemm_bf16<MODE_AT, float><<<dim3(12, 32), blk, 0, stream>>>(
        gin, Wr_bf, br, nullptr, a_t, nullptr, 4096, D1, ED,
        sumsq + 2 * 4096, nullptr);

    fft_a_kernel<<<768, blk, 0, stream>>>(a_t, (float2*)Wspec);
    fft_conv_kernel<<<3072, blk, 0, stream>>>(
        v_t, (const float2*)Wspec, u_t, gated_t);

    transpose_cs_kernel<<<dim3(24, 128), blk, 0, stream>>>(gated_t, gated);

    gemm_bf16<MODE_PLAIN, float><<<dim3(4, 64), blk, 0, stream>>>(
        gated, Wo_bf, bo, nullptr, out, nullptr, 8192, ED, D1,
        nullptr, nullptr);
}